// Round 2
// baseline (1345.027 us; speedup 1.0000x reference)
//
#include <hip/hip_runtime.h>
#include <hip/hip_bf16.h>

// ---------------------------------------------------------------------------
// SharedSpecialistMoEFFN on MI355X (gfx950) — round 5
//
// R4 post-mortem: 256x256 coarse 2-phase dbuf regressed (468us vs R3 354us,
// MfmaUtil 19%): 1 block/CU + 2 barriers/K-tile + only 1-tile prefetch depth
// = whole-CU stalls every tile (the documented m196 "coarse phase-split"
// failure). Correctness of 256^2 staging/swizzle/epilogue verified though.
// R5: keep 256x256 / 8 waves, switch to QUAD-buffered BK=32 K-tiles
// (4 x 16KB x 2 ops = 128 KiB, same LDS). Depth-3 prefetch with COUNTED
// vmcnt(8): per tile issue stage of t+3, ds_read tile t, 32 MFMA, vmcnt(8)
// (retires exactly tile t+1; t+2/t+3 stay in flight ACROSS the barrier),
// ONE barrier. Never drains in steady state (T4). Swizzle: slot=qd^(lr&3)
// (4 slots/row at BK=32); worst-case 2-way LDS aliasing = free (m136).
// ---------------------------------------------------------------------------

#define D_MODEL 1024
#define D_FF    4096
#define N_EXP   8
#define T_TOK   8192

typedef _Float16 half8  __attribute__((ext_vector_type(8)));
typedef _Float16 half4v __attribute__((ext_vector_type(4)));
typedef float    floatx4 __attribute__((ext_vector_type(4)));

__device__ __forceinline__ float gelu_exact(float x) {
  return 0.5f * x * (1.0f + erff(x * 0.70710678118654752f));
}

__device__ __forceinline__ void gld_lds16(const _Float16* g, _Float16* l) {
  __builtin_amdgcn_global_load_lds(
      (const __attribute__((address_space(1))) void*)g,
      (__attribute__((address_space(3))) void*)l, 16, 0, 0);
}

// ---------------------------------------------------------------- converts
__global__ void convert_f32_f16(const float* __restrict__ src,
                                _Float16* __restrict__ dst, int n4) {
  int i = blockIdx.x * blockDim.x + threadIdx.x;
  if (i >= n4) return;
  float4 v = ((const float4*)src)[i];
  half4v h;
  h[0] = (_Float16)v.x; h[1] = (_Float16)v.y;
  h[2] = (_Float16)v.z; h[3] = (_Float16)v.w;
  ((half4v*)dst)[i] = h;
}

// z=0: shared weight, z>=1: expert z-1.  src fp32 [R][C] -> dst fp16 [C][R]
__global__ void transpose_convert9(const float* __restrict__ srcSh,
                                   const float* __restrict__ srcEx,
                                   _Float16* __restrict__ dst, int R, int C) {
  const size_t msz = (size_t)R * C;
  const float* src = (blockIdx.z == 0) ? srcSh : srcEx + msz * (blockIdx.z - 1);
  _Float16* d = dst + msz * blockIdx.z;
  __shared__ float tile[32][33];
  int c0 = blockIdx.x * 32, r0 = blockIdx.y * 32;
  int tx = threadIdx.x, ty = threadIdx.y;   // block (32, 8)
#pragma unroll
  for (int i = 0; i < 4; ++i)
    tile[ty + i * 8][tx] = src[(size_t)(r0 + ty + i * 8) * C + c0 + tx];
  __syncthreads();
#pragma unroll
  for (int i = 0; i < 4; ++i)
    d[(size_t)(c0 + ty + i * 8) * R + r0 + tx] = (_Float16)tile[tx][ty + i * 8];
}

// ---------------------------------------------------------------- router
__global__ void router_kernel(const float* __restrict__ x,
                              const float* __restrict__ rw,
                              const float* __restrict__ rb,
                              int* __restrict__ sel_idx,
                              float* __restrict__ sel_w,
                              int* __restrict__ counts) {
  int lane = threadIdx.x & 63;
  int t = blockIdx.x * 4 + (threadIdx.x >> 6);
  const float* xr = x + (size_t)t * D_MODEL;
  float acc[N_EXP];
#pragma unroll
  for (int e = 0; e < N_EXP; ++e) acc[e] = 0.f;
  for (int k = lane; k < D_MODEL; k += 64) {
    float xv = xr[k];
    const float* w = rw + (size_t)k * N_EXP;
#pragma unroll
    for (int e = 0; e < N_EXP; ++e) acc[e] += xv * w[e];
  }
#pragma unroll
  for (int off = 32; off > 0; off >>= 1) {
#pragma unroll
    for (int e = 0; e < N_EXP; ++e)
      acc[e] += __shfl_down(acc[e], off, 64);
  }
  if (lane == 0) {
    float mx = -1e30f;
#pragma unroll
    for (int e = 0; e < N_EXP; ++e) { acc[e] += rb[e]; mx = fmaxf(mx, acc[e]); }
    float p[N_EXP], s = 0.f;
#pragma unroll
    for (int e = 0; e < N_EXP; ++e) { p[e] = expf(acc[e] - mx); s += p[e]; }
    float inv = 1.f / s;
#pragma unroll
    for (int e = 0; e < N_EXP; ++e) p[e] *= inv;
    int i0 = 0; float p0 = p[0];
#pragma unroll
    for (int e = 1; e < N_EXP; ++e) if (p[e] > p0) { p0 = p[e]; i0 = e; }
    int i1 = -1; float p1 = -1.f;
#pragma unroll
    for (int e = 0; e < N_EXP; ++e)
      if (e != i0 && p[e] > p1) { p1 = p[e]; i1 = e; }
    float s2 = p0 + p1 + 1e-9f;
    sel_idx[2 * t] = i0; sel_idx[2 * t + 1] = i1;
    sel_w[2 * t] = p0 / s2; sel_w[2 * t + 1] = p1 / s2;
    atomicAdd(&counts[i0 * 32], 1);
    atomicAdd(&counts[i1 * 32], 1);
  }
}

__global__ void scan_kernel(const int* __restrict__ counts,
                            int* __restrict__ offsets,
                            int* __restrict__ cursor) {
  if (threadIdx.x == 0) {
    int s = 0;
    for (int e = 0; e < N_EXP; ++e) {
      offsets[e] = s; cursor[e * 32] = s; s += counts[e * 32];
    }
    offsets[N_EXP] = s;
  }
}

__global__ void assign_kernel(const int* __restrict__ sel_idx,
                              int* __restrict__ cursor,
                              int* __restrict__ rows,
                              int* __restrict__ inv) {
  int t = blockIdx.x * blockDim.x + threadIdx.x;
  if (t >= T_TOK) return;
#pragma unroll
  for (int k = 0; k < 2; ++k) {
    int e = sel_idx[2 * t + k];
    int pos = atomicAdd(&cursor[e * 32], 1);
    rows[pos] = t;
    inv[2 * t + k] = pos;
  }
}

// ---------------------------------------------------------------- GEMM
// 256x256 tile, BK=32, 512 threads = 8 waves (2M x 4N), per-wave 128x64 out.
// LDS: QUAD-buffered A[4][256][32] + B[4][256][32] fp16 = 128 KiB.
// Iteration t:  stage tile t+3 -> buf (t+3)&3   (4 x global_load_lds, legal:
//               that buf was read at t-1, published by t-1's barrier)
//               ds_read tile t frags (12 x ds_read_b128; compiler lgkmcnt)
//               setprio(1) 32 MFMA setprio(0)
//               s_waitcnt vmcnt(8)   <- retires exactly tile t+1's 4 loads;
//                                       tiles t+2,t+3 stay in flight ACROSS
//               s_barrier               the barrier (T4: never drain)
// Tail: vmcnt(4) at t==NT-3, vmcnt(0) after. Prologue: stage 0,1,2; vmcnt(8);
// barrier. Swizzle: row r slot p holds k-chunk p^(r&3); read slot qd^(lr&3).
template <int PHASE>
__global__ __launch_bounds__(512, 2) void gemm_kernel(
    const _Float16* __restrict__ A, const _Float16* __restrict__ Wt,
    const float* __restrict__ biasSh, const float* __restrict__ biasEx,
    _Float16* __restrict__ Hout, float* __restrict__ out,
    float* __restrict__ Yexp, const int* __restrict__ rows,
    const int* __restrict__ counts, const int* __restrict__ offsets) {
  constexpr int K = (PHASE == 1) ? D_MODEL : D_FF;
  constexpr int N = (PHASE == 1) ? D_FF : D_MODEL;
  constexpr int BK2 = 32;
  constexpr int NT = K / BK2;               // 32 (phase1) / 128 (phase2)
  constexpr int TSZ = 256 * BK2;            // halfs per operand buffer
  const int z = blockIdx.z;
  int M = T_TOK, offs = 0;
  if (z > 0) {
    M = counts[(z - 1) * 32];
    offs = offsets[z - 1];
    if ((int)blockIdx.y * 256 >= M) return;   // uniform early-exit
  }
  const int tid = threadIdx.x, lane = tid & 63, wid = tid >> 6;
  const int m0 = blockIdx.y * 256, n0 = blockIdx.x * 256;
  const _Float16* Wz = Wt + (size_t)z * N * K;

  __shared__ __align__(16) _Float16 As[4 * TSZ];   // 64 KiB
  __shared__ __align__(16) _Float16 Bs[4 * TSZ];   // 64 KiB

  // staging: wave w covers rows w*32..w*32+31 in two 16-row ops (j=0,1).
  // lane i -> row sub=i>>2 of the op, physical slot p=i&3 holding GLOBAL
  // k-chunk g = p ^ (sub&3)  (row&3 == sub&3 since row bases are x16).
  const int sub = lane >> 2;                  // 0..15
  const int g = (lane & 3) ^ (sub & 3);

  size_t grA0, grA1;
  {
    int r0 = m0 + wid * 32 + 0 * 16 + sub;
    int r1 = m0 + wid * 32 + 1 * 16 + sub;
    if (z == 0) {
      grA0 = (size_t)r0; grA1 = (size_t)r1;
    } else {
      int c0 = r0 < M ? r0 : M - 1;
      int c1 = r1 < M ? r1 : M - 1;
      if constexpr (PHASE == 1) {
        grA0 = (size_t)rows[offs + c0];
        grA1 = (size_t)rows[offs + c1];
      } else {
        grA0 = (size_t)(T_TOK + offs + c0);
        grA1 = (size_t)(T_TOK + offs + c1);
      }
    }
  }
  const _Float16* aS0 = A + grA0 * K + g * 8;
  const _Float16* aS1 = A + grA1 * K + g * 8;
  const _Float16* bS0 = Wz + (size_t)(n0 + wid * 32 + 0 * 16 + sub) * K + g * 8;
  const _Float16* bS1 = Wz + (size_t)(n0 + wid * 32 + 1 * 16 + sub) * K + g * 8;
  const int ldsOff = wid * 32 * BK2;          // wave's row block (halfs)

  auto STAGE = [&](int b) {
    _Float16* Ad = As + b * TSZ + ldsOff;
    _Float16* Bd = Bs + b * TSZ + ldsOff;
    gld_lds16(aS0, Ad);             aS0 += BK2;
    gld_lds16(aS1, Ad + 16 * BK2);  aS1 += BK2;
    gld_lds16(bS0, Bd);             bS0 += BK2;
    gld_lds16(bS1, Bd + 16 * BK2);  bS1 += BK2;
  };

  floatx4 acc[8][4] = {};
  const int wm = wid >> 2, wn = wid & 3;      // 2 x 4 wave grid
  const int lr = lane & 15, qd = lane >> 4;
  const int rslot = (qd ^ (lr & 3)) * 8;      // k-chunk slot (row&3 == lr&3)

  // prologue: stage tiles 0,1,2 into bufs 0,1,2 (12 loads/thread)
  STAGE(0); STAGE(1); STAGE(2);
  asm volatile("s_waitcnt vmcnt(8)" ::: "memory");  // tile 0 landed
  __builtin_amdgcn_s_barrier();

  for (int t = 0; t < NT; ++t) {
    if (t + 3 < NT) STAGE((t + 3) & 3);
    const _Float16* Ac = As + (t & 3) * TSZ;
    const _Float16* Bc = Bs + (t & 3) * TSZ;
    half8 af[8], bf[4];
#pragma unroll
    for (int mi = 0; mi < 8; ++mi)
      af[mi] = *(const half8*)(Ac + (wm * 128 + mi * 16 + lr) * BK2 + rslot);
#pragma unroll
    for (int ni = 0; ni < 4; ++ni)
      bf[ni] = *(const half8*)(Bc + (wn * 64 + ni * 16 + lr) * BK2 + rslot);
    __builtin_amdgcn_s_setprio(1);
#pragma unroll
    for (int mi = 0; mi < 8; ++mi)
#pragma unroll
      for (int ni = 0; ni < 4; ++ni)
        acc[mi][ni] = __builtin_amdgcn_mfma_f32_16x16x32_f16(
            af[mi], bf[ni], acc[mi][ni], 0, 0, 0);
    __builtin_amdgcn_s_setprio(0);
    // counted wait: tile t+1 must be landed after the barrier; keep the
    // rest (up to 8 loads = tiles t+2,t+3) in flight across it.
    if (t + 3 < NT) {
      asm volatile("s_waitcnt vmcnt(8)" ::: "memory");
    } else if (t + 3 == NT) {
      asm volatile("s_waitcnt vmcnt(4)" ::: "memory");
    } else {
      asm volatile("s_waitcnt vmcnt(0)" ::: "memory");
    }
    __builtin_amdgcn_s_barrier();
  }

  // epilogue: C/D layout col=lane&15, row=quad*4+reg (R1-verified)
  const float* be = (z == 0) ? biasSh : biasEx + (size_t)(z - 1) * N;
#pragma unroll
  for (int mi = 0; mi < 8; ++mi) {
#pragma unroll
    for (int ni = 0; ni < 4; ++ni) {
      floatx4 v = acc[mi][ni];
#pragma unroll
      for (int r4 = 0; r4 < 4; ++r4) {
        const int lrow = m0 + wm * 128 + mi * 16 + qd * 4 + r4;  // row in segment
        const int col = n0 + wn * 64 + ni * 16 + lr;
        const float val = v[r4] + be[col];
        if constexpr (PHASE == 1) {
          if (z == 0) {
            Hout[(size_t)lrow * N + col] = (_Float16)gelu_exact(val);
          } else if (lrow < M) {
            Hout[(size_t)(T_TOK + offs + lrow) * N + col] =
                (_Float16)gelu_exact(val);
          }
        } else {
          if (z == 0) {
            out[(size_t)lrow * N + col] = val;
          } else if (lrow < M) {
            Yexp[(size_t)(offs + lrow) * N + col] = val;
          }
        }
      }
    }
  }
}

// ---------------------------------------------------------------- combine
// out[t] = out[t] (shared FFN2) + w0*Yexp[p0] + w1*Yexp[p1]
__global__ void combine_kernel(float* __restrict__ out,
                               const float* __restrict__ Yexp,
                               const int* __restrict__ inv,
                               const float* __restrict__ selw) {
  const int t = blockIdx.x;
  const int c = threadIdx.x * 4;
  const int p0 = inv[2 * t], p1 = inv[2 * t + 1];
  const float w0 = selw[2 * t], w1 = selw[2 * t + 1];
  float4 o = *(float4*)(out + (size_t)t * D_MODEL + c);
  const float4 a = *(const float4*)(Yexp + (size_t)p0 * D_MODEL + c);
  const float4 b = *(const float4*)(Yexp + (size_t)p1 * D_MODEL + c);
  o.x += w0 * a.x + w1 * b.x;
  o.y += w0 * a.y + w1 * b.y;
  o.z += w0 * a.z + w1 * b.z;
  o.w += w0 * a.w + w1 * b.w;
  *(float4*)(out + (size_t)t * D_MODEL + c) = o;
}

// ---------------------------------------------------------------- launch
extern "C" void kernel_launch(void* const* d_in, const int* in_sizes, int n_in,
                              void* d_out, int out_size, void* d_ws,
                              size_t ws_size, hipStream_t stream) {
  const float* x   = (const float*)d_in[0];
  const float* sw1 = (const float*)d_in[1];
  const float* sb1 = (const float*)d_in[2];
  const float* sw2 = (const float*)d_in[3];
  const float* sb2 = (const float*)d_in[4];
  const float* rw  = (const float*)d_in[5];
  const float* rb  = (const float*)d_in[6];
  const float* ew1 = (const float*)d_in[7];
  const float* eb1 = (const float*)d_in[8];
  const float* ew2 = (const float*)d_in[9];
  const float* eb2 = (const float*)d_in[10];
  float* out = (float*)d_out;

  char* ws = (char*)d_ws;
  size_t off = 0;
  auto alloc = [&](size_t bytes) {
    void* p = ws + off;
    off += (bytes + 255) & ~(size_t)255;
    return p;
  };
  _Float16* xb  = (_Float16*)alloc((size_t)T_TOK * D_MODEL * 2);        // 16 MB
  _Float16* w2t = (_Float16*)alloc((size_t)9 * D_MODEL * D_FF * 2);     // 72 MB
  _Float16* H   = (_Float16*)alloc((size_t)3 * T_TOK * D_FF * 2);       // 201 MB
  _Float16* w1t = (_Float16*)alloc((size_t)9 * D_FF * D_MODEL * 2);     // 72 MB
  float* Yexp   = (float*)w1t;  // alias: w1t dead after FFN1, Yexp 67 MB
  int*   sel_idx = (int*)alloc((size_t)T_TOK * 2 * 4);
  float* sel_w   = (float*)alloc((size_t)T_TOK * 2 * 4);
  int*   rows    = (int*)alloc((size_t)2 * T_TOK * 4);
  int*   inv     = (int*)alloc((size_t)2 * T_TOK * 4);
  int*   counts  = (int*)alloc(N_EXP * 32 * 4);
  int*   offsets = (int*)alloc(16 * 4);
  int*   cursor  = (int*)alloc(N_EXP * 32 * 4);
  (void)ws_size; (void)in_sizes; (void)n_in; (void)out_size;

  hipMemsetAsync(counts, 0, N_EXP * 32 * 4, stream);

  convert_f32_f16<<<(T_TOK * D_MODEL / 4 + 255) / 256, 256, 0, stream>>>(
      x, xb, T_TOK * D_MODEL / 4);
  dim3 tb(32, 8);
  // W1: [1024][4096] -> [4096][1024];  W2: [4096][1024] -> [1024][4096]
  transpose_convert9<<<dim3(D_FF / 32, D_MODEL / 32, 9), tb, 0, stream>>>(
      sw1, ew1, w1t, D_MODEL, D_FF);
  transpose_convert9<<<dim3(D_MODEL / 32, D_FF / 32, 9), tb, 0, stream>>>(
      sw2, ew2, w2t, D_FF, D_MODEL);

  router_kernel<<<T_TOK / 4, 256, 0, stream>>>(x, rw, rb, sel_idx, sel_w, counts);
  scan_kernel<<<1, 64, 0, stream>>>(counts, offsets, cursor);
  assign_kernel<<<T_TOK / 256, 256, 0, stream>>>(sel_idx, cursor, rows, inv);

  gemm_kernel<1><<<dim3(D_FF / 256, T_TOK / 256, 9), 512, 0, stream>>>(
      xb, w1t, sb1, eb1, H, nullptr, nullptr, rows, counts, offsets);
  gemm_kernel<2><<<dim3(D_MODEL / 256, T_TOK / 256, 9), 512, 0, stream>>>(
      H, w2t, sb2, eb2, nullptr, out, Yexp, rows, counts, offsets);

  combine_kernel<<<T_TOK, 256, 0, stream>>>(out, Yexp, inv, sel_w);
}

// Round 3
// 1107.665 us; speedup vs baseline: 1.2143x; 1.2143x over previous
//
#include <hip/hip_runtime.h>
#include <hip/hip_bf16.h>

// ---------------------------------------------------------------------------
// SharedSpecialistMoEFFN on MI355X (gfx950) — round 6
//
// R4/R5 post-mortem: both 256^2 pipeline attempts regressed (468/528 vs R3's
// 354us gemm1). R5 additionally hit 1.97e7 LDS bank conflicts: BK=32 rows are
// 64B so the XOR family can't spread 16 lanes over 32 banks. Lesson (matches
// m196/m248): anything between "m97 2-barrier @128^2 with 2.5 blocks/CU" and
// the full 8-phase combo is worse than both; 8-phase from prose spec keeps
// producing racy ledgers -> dropped.
// R6: revert to the verified R3 structure (128^2, BK=64, single-buffer,
// sync->stage->vmcnt(0)->sync->compute) and add two in-structure levers:
//  1. T1 XCD swizzle: all blocks sharing a B(N-column)-panel -> same XCD, so
//     staged W-loads become L2 hits (~200cy) instead of HBM (~900cy),
//     shrinking the per-K-step drain. Bijective per z-slice; grid%8==0 keeps
//     the phase across z.
//  2. 32x32x16 MFMA: half the MFMA issue slots, ~15% higher pipe ceiling.
//     A/B frags: row=lane&31, k-chunk=ks*2+(lane>>5); slot=chunk^(row&7)
//     (same verified conflict-free family). C/D: col=lane&31,
//     row=(reg&3)+8*(reg>>2)+4*(lane>>5)  (guide m74/m101 HW-verified).
// ---------------------------------------------------------------------------

#define D_MODEL 1024
#define D_FF    4096
#define N_EXP   8
#define T_TOK   8192
#define BK      64

typedef _Float16 half8  __attribute__((ext_vector_type(8)));
typedef _Float16 half4v __attribute__((ext_vector_type(4)));
typedef float    floatx16 __attribute__((ext_vector_type(16)));

__device__ __forceinline__ float gelu_exact(float x) {
  return 0.5f * x * (1.0f + erff(x * 0.70710678118654752f));
}

__device__ __forceinline__ void gld_lds16(const _Float16* g, _Float16* l) {
  __builtin_amdgcn_global_load_lds(
      (const __attribute__((address_space(1))) void*)g,
      (__attribute__((address_space(3))) void*)l, 16, 0, 0);
}

// ---------------------------------------------------------------- converts
__global__ void convert_f32_f16(const float* __restrict__ src,
                                _Float16* __restrict__ dst, int n4) {
  int i = blockIdx.x * blockDim.x + threadIdx.x;
  if (i >= n4) return;
  float4 v = ((const float4*)src)[i];
  half4v h;
  h[0] = (_Float16)v.x; h[1] = (_Float16)v.y;
  h[2] = (_Float16)v.z; h[3] = (_Float16)v.w;
  ((half4v*)dst)[i] = h;
}

// z=0: shared weight, z>=1: expert z-1.  src fp32 [R][C] -> dst fp16 [C][R]
__global__ void transpose_convert9(const float* __restrict__ srcSh,
                                   const float* __restrict__ srcEx,
                                   _Float16* __restrict__ dst, int R, int C) {
  const size_t msz = (size_t)R * C;
  const float* src = (blockIdx.z == 0) ? srcSh : srcEx + msz * (blockIdx.z - 1);
  _Float16* d = dst + msz * blockIdx.z;
  __shared__ float tile[32][33];
  int c0 = blockIdx.x * 32, r0 = blockIdx.y * 32;
  int tx = threadIdx.x, ty = threadIdx.y;   // block (32, 8)
#pragma unroll
  for (int i = 0; i < 4; ++i)
    tile[ty + i * 8][tx] = src[(size_t)(r0 + ty + i * 8) * C + c0 + tx];
  __syncthreads();
#pragma unroll
  for (int i = 0; i < 4; ++i)
    d[(size_t)(c0 + ty + i * 8) * R + r0 + tx] = (_Float16)tile[tx][ty + i * 8];
}

// ---------------------------------------------------------------- router
__global__ void router_kernel(const float* __restrict__ x,
                              const float* __restrict__ rw,
                              const float* __restrict__ rb,
                              int* __restrict__ sel_idx,
                              float* __restrict__ sel_w,
                              int* __restrict__ counts) {
  int lane = threadIdx.x & 63;
  int t = blockIdx.x * 4 + (threadIdx.x >> 6);
  const float* xr = x + (size_t)t * D_MODEL;
  float acc[N_EXP];
#pragma unroll
  for (int e = 0; e < N_EXP; ++e) acc[e] = 0.f;
  for (int k = lane; k < D_MODEL; k += 64) {
    float xv = xr[k];
    const float* w = rw + (size_t)k * N_EXP;
#pragma unroll
    for (int e = 0; e < N_EXP; ++e) acc[e] += xv * w[e];
  }
#pragma unroll
  for (int off = 32; off > 0; off >>= 1) {
#pragma unroll
    for (int e = 0; e < N_EXP; ++e)
      acc[e] += __shfl_down(acc[e], off, 64);
  }
  if (lane == 0) {
    float mx = -1e30f;
#pragma unroll
    for (int e = 0; e < N_EXP; ++e) { acc[e] += rb[e]; mx = fmaxf(mx, acc[e]); }
    float p[N_EXP], s = 0.f;
#pragma unroll
    for (int e = 0; e < N_EXP; ++e) { p[e] = expf(acc[e] - mx); s += p[e]; }
    float inv = 1.f / s;
#pragma unroll
    for (int e = 0; e < N_EXP; ++e) p[e] *= inv;
    int i0 = 0; float p0 = p[0];
#pragma unroll
    for (int e = 1; e < N_EXP; ++e) if (p[e] > p0) { p0 = p[e]; i0 = e; }
    int i1 = -1; float p1 = -1.f;
#pragma unroll
    for (int e = 0; e < N_EXP; ++e)
      if (e != i0 && p[e] > p1) { p1 = p[e]; i1 = e; }
    float s2 = p0 + p1 + 1e-9f;
    sel_idx[2 * t] = i0; sel_idx[2 * t + 1] = i1;
    sel_w[2 * t] = p0 / s2; sel_w[2 * t + 1] = p1 / s2;
    atomicAdd(&counts[i0 * 32], 1);
    atomicAdd(&counts[i1 * 32], 1);
  }
}

__global__ void scan_kernel(const int* __restrict__ counts,
                            int* __restrict__ offsets,
                            int* __restrict__ cursor) {
  if (threadIdx.x == 0) {
    int s = 0;
    for (int e = 0; e < N_EXP; ++e) {
      offsets[e] = s; cursor[e * 32] = s; s += counts[e * 32];
    }
    offsets[N_EXP] = s;
  }
}

__global__ void assign_kernel(const int* __restrict__ sel_idx,
                              int* __restrict__ cursor,
                              int* __restrict__ rows,
                              int* __restrict__ inv) {
  int t = blockIdx.x * blockDim.x + threadIdx.x;
  if (t >= T_TOK) return;
#pragma unroll
  for (int k = 0; k < 2; ++k) {
    int e = sel_idx[2 * t + k];
    int pos = atomicAdd(&cursor[e * 32], 1);
    rows[pos] = t;
    inv[2 * t + k] = pos;
  }
}

// ---------------------------------------------------------------- GEMM
// 128x128 tile, BK=64, 256 thr (2x2 waves of 64x64), XOR-swizzled staging
// (verified 0-conflict), R3 sync structure. 32x32x16 MFMA: per K-tile per
// wave 16 ds_read_b128 + 16 MFMA (was 16+32 with 16x16x32).
// XCD swizzle: L = by*GX+bx; bx' groups same-N-panel blocks on one XCD so
// W stays L2-resident (GX=32 -> 4 panels/XCD = 1MB; GX=8 -> 1 panel = 1MB).
template <int PHASE>
__global__ __launch_bounds__(256, 3) void gemm_kernel(
    const _Float16* __restrict__ A, const _Float16* __restrict__ Wt,
    const float* __restrict__ biasSh, const float* __restrict__ biasEx,
    _Float16* __restrict__ Hout, float* __restrict__ out,
    float* __restrict__ Yexp, const int* __restrict__ rows,
    const int* __restrict__ counts, const int* __restrict__ offsets) {
  constexpr int K = (PHASE == 1) ? D_MODEL : D_FF;
  constexpr int N = (PHASE == 1) ? D_FF : D_MODEL;
  constexpr int GX = N / 128;               // 32 (phase1) / 8 (phase2)
  constexpr int CPX = GX / 8;               // x-columns per XCD: 4 / 1
  // ---- T1: bijective XCD remap (round-robin assumption; speed-only)
  const int L = (int)blockIdx.y * GX + (int)blockIdx.x;
  const int bx = (L & 7) * CPX + ((L >> 3) % CPX);
  const int by = (L >> 3) / CPX;

  const int z = blockIdx.z;
  int M = T_TOK, offs = 0;
  if (z > 0) {
    M = counts[(z - 1) * 32];
    offs = offsets[z - 1];
    if (by * 128 >= M) return;              // uniform early-exit
  }
  const int tid = threadIdx.x, lane = tid & 63, wid = tid >> 6;
  const int m0 = by * 128, n0 = bx * 128;
  const _Float16* Wz = Wt + (size_t)z * N * K;

  __shared__ __align__(16) _Float16 As[128 * BK];  // [m][k], k-chunks swizzled
  __shared__ __align__(16) _Float16 Bs[128 * BK];  // [n][k]

  // staging: 16 chunk-groups of 8 rows x 128 B; wave w fills groups 4w..4w+3.
  // lane i -> row sub=i>>3 of the group, physical 16B slot p=i&7 holding
  // GLOBAL k-chunk g = p ^ sub  (XOR swizzle).
  const int sub = lane >> 3, pp = lane & 7, g = pp ^ sub;

  int r0i = m0 + (wid * 4 + 0) * 8 + sub;
  int r1i = m0 + (wid * 4 + 1) * 8 + sub;
  int r2i = m0 + (wid * 4 + 2) * 8 + sub;
  int r3i = m0 + (wid * 4 + 3) * 8 + sub;
  size_t gr0, gr1, gr2, gr3;
  if (z == 0) {
    gr0 = (size_t)r0i; gr1 = (size_t)r1i; gr2 = (size_t)r2i; gr3 = (size_t)r3i;
  } else if constexpr (PHASE == 1) {
    gr0 = (size_t)rows[offs + (r0i < M ? r0i : M - 1)];
    gr1 = (size_t)rows[offs + (r1i < M ? r1i : M - 1)];
    gr2 = (size_t)rows[offs + (r2i < M ? r2i : M - 1)];
    gr3 = (size_t)rows[offs + (r3i < M ? r3i : M - 1)];
  } else {
    gr0 = (size_t)(T_TOK + offs + (r0i < M ? r0i : M - 1));
    gr1 = (size_t)(T_TOK + offs + (r1i < M ? r1i : M - 1));
    gr2 = (size_t)(T_TOK + offs + (r2i < M ? r2i : M - 1));
    gr3 = (size_t)(T_TOK + offs + (r3i < M ? r3i : M - 1));
  }
  const _Float16* aS0 = A + gr0 * K + g * 8;
  const _Float16* aS1 = A + gr1 * K + g * 8;
  const _Float16* aS2 = A + gr2 * K + g * 8;
  const _Float16* aS3 = A + gr3 * K + g * 8;
  const _Float16* bS0 = Wz + (size_t)(n0 + (wid * 4 + 0) * 8 + sub) * K + g * 8;
  const _Float16* bS1 = Wz + (size_t)(n0 + (wid * 4 + 1) * 8 + sub) * K + g * 8;
  const _Float16* bS2 = Wz + (size_t)(n0 + (wid * 4 + 2) * 8 + sub) * K + g * 8;
  const _Float16* bS3 = Wz + (size_t)(n0 + (wid * 4 + 3) * 8 + sub) * K + g * 8;

  floatx16 acc[2][2] = {};
  const int wm = wid >> 1, wn = wid & 1;    // 2x2 wave grid, 64x64 each
  const int l31 = lane & 31, lh = lane >> 5;
  const int x7 = l31 & 7;                   // row&7 for all frag rows

  for (int kt = 0; kt < K; kt += BK) {
    __syncthreads();
    gld_lds16(aS0, As + (wid * 4 + 0) * 512);
    gld_lds16(aS1, As + (wid * 4 + 1) * 512);
    gld_lds16(aS2, As + (wid * 4 + 2) * 512);
    gld_lds16(aS3, As + (wid * 4 + 3) * 512);
    gld_lds16(bS0, Bs + (wid * 4 + 0) * 512);
    gld_lds16(bS1, Bs + (wid * 4 + 1) * 512);
    gld_lds16(bS2, Bs + (wid * 4 + 2) * 512);
    gld_lds16(bS3, Bs + (wid * 4 + 3) * 512);
    aS0 += BK; aS1 += BK; aS2 += BK; aS3 += BK;
    bS0 += BK; bS1 += BK; bS2 += BK; bS3 += BK;
    asm volatile("s_waitcnt vmcnt(0)" ::: "memory");
    __syncthreads();
#pragma unroll
    for (int ks = 0; ks < 4; ++ks) {        // 4 k-steps of 16
      const int slot = ((ks * 2 + lh) ^ x7) * 8;
      half8 af[2], bf[2];
#pragma unroll
      for (int mi = 0; mi < 2; ++mi)
        af[mi] = *(const half8*)(As + (wm * 64 + mi * 32 + l31) * BK + slot);
#pragma unroll
      for (int ni = 0; ni < 2; ++ni)
        bf[ni] = *(const half8*)(Bs + (wn * 64 + ni * 32 + l31) * BK + slot);
#pragma unroll
      for (int mi = 0; mi < 2; ++mi)
#pragma unroll
        for (int ni = 0; ni < 2; ++ni)
          acc[mi][ni] = __builtin_amdgcn_mfma_f32_32x32x16_f16(
              af[mi], bf[ni], acc[mi][ni], 0, 0, 0);
    }
  }

  // epilogue: 32x32 C/D layout col=lane&31, row=(reg&3)+8*(reg>>2)+4*(lane>>5)
  const float* be = (z == 0) ? biasSh : biasEx + (size_t)(z - 1) * N;
#pragma unroll
  for (int mi = 0; mi < 2; ++mi) {
#pragma unroll
    for (int ni = 0; ni < 2; ++ni) {
      floatx16 v = acc[mi][ni];
      const int col = n0 + wn * 64 + ni * 32 + l31;
      const float bias = be[col];
#pragma unroll
      for (int r4 = 0; r4 < 4; ++r4) {
#pragma unroll
        for (int j = 0; j < 4; ++j) {
          const int lrow = m0 + wm * 64 + mi * 32 + 4 * lh + 8 * r4 + j;
          const float val = v[r4 * 4 + j] + bias;
          if constexpr (PHASE == 1) {
            if (z == 0) {
              Hout[(size_t)lrow * N + col] = (_Float16)gelu_exact(val);
            } else if (lrow < M) {
              Hout[(size_t)(T_TOK + offs + lrow) * N + col] =
                  (_Float16)gelu_exact(val);
            }
          } else {
            if (z == 0) {
              out[(size_t)lrow * N + col] = val;
            } else if (lrow < M) {
              Yexp[(size_t)(offs + lrow) * N + col] = val;
            }
          }
        }
      }
    }
  }
}

// ---------------------------------------------------------------- combine
// out[t] = out[t] (shared FFN2) + w0*Yexp[p0] + w1*Yexp[p1]
__global__ void combine_kernel(float* __restrict__ out,
                               const float* __restrict__ Yexp,
                               const int* __restrict__ inv,
                               const float* __restrict__ selw) {
  const int t = blockIdx.x;
  const int c = threadIdx.x * 4;
  const int p0 = inv[2 * t], p1 = inv[2 * t + 1];
  const float w0 = selw[2 * t], w1 = selw[2 * t + 1];
  float4 o = *(float4*)(out + (size_t)t * D_MODEL + c);
  const float4 a = *(const float4*)(Yexp + (size_t)p0 * D_MODEL + c);
  const float4 b = *(const float4*)(Yexp + (size_t)p1 * D_MODEL + c);
  o.x += w0 * a.x + w1 * b.x;
  o.y += w0 * a.y + w1 * b.y;
  o.z += w0 * a.z + w1 * b.z;
  o.w += w0 * a.w + w1 * b.w;
  *(float4*)(out + (size_t)t * D_MODEL + c) = o;
}

// ---------------------------------------------------------------- launch
extern "C" void kernel_launch(void* const* d_in, const int* in_sizes, int n_in,
                              void* d_out, int out_size, void* d_ws,
                              size_t ws_size, hipStream_t stream) {
  const float* x   = (const float*)d_in[0];
  const float* sw1 = (const float*)d_in[1];
  const float* sb1 = (const float*)d_in[2];
  const float* sw2 = (const float*)d_in[3];
  const float* sb2 = (const float*)d_in[4];
  const float* rw  = (const float*)d_in[5];
  const float* rb  = (const float*)d_in[6];
  const float* ew1 = (const float*)d_in[7];
  const float* eb1 = (const float*)d_in[8];
  const float* ew2 = (const float*)d_in[9];
  const float* eb2 = (const float*)d_in[10];
  float* out = (float*)d_out;

  char* ws = (char*)d_ws;
  size_t off = 0;
  auto alloc = [&](size_t bytes) {
    void* p = ws + off;
    off += (bytes + 255) & ~(size_t)255;
    return p;
  };
  _Float16* xb  = (_Float16*)alloc((size_t)T_TOK * D_MODEL * 2);        // 16 MB
  _Float16* w2t = (_Float16*)alloc((size_t)9 * D_MODEL * D_FF * 2);     // 72 MB
  _Float16* H   = (_Float16*)alloc((size_t)3 * T_TOK * D_FF * 2);       // 201 MB
  _Float16* w1t = (_Float16*)alloc((size_t)9 * D_FF * D_MODEL * 2);     // 72 MB
  float* Yexp   = (float*)w1t;  // alias: w1t dead after FFN1, Yexp 67 MB
  int*   sel_idx = (int*)alloc((size_t)T_TOK * 2 * 4);
  float* sel_w   = (float*)alloc((size_t)T_TOK * 2 * 4);
  int*   rows    = (int*)alloc((size_t)2 * T_TOK * 4);
  int*   inv     = (int*)alloc((size_t)2 * T_TOK * 4);
  int*   counts  = (int*)alloc(N_EXP * 32 * 4);
  int*   offsets = (int*)alloc(16 * 4);
  int*   cursor  = (int*)alloc(N_EXP * 32 * 4);
  (void)ws_size; (void)in_sizes; (void)n_in; (void)out_size;

  hipMemsetAsync(counts, 0, N_EXP * 32 * 4, stream);

  convert_f32_f16<<<(T_TOK * D_MODEL / 4 + 255) / 256, 256, 0, stream>>>(
      x, xb, T_TOK * D_MODEL / 4);
  dim3 tb(32, 8);
  // W1: [1024][4096] -> [4096][1024];  W2: [4096][1024] -> [1024][4096]
  transpose_convert9<<<dim3(D_FF / 32, D_MODEL / 32, 9), tb, 0, stream>>>(
      sw1, ew1, w1t, D_MODEL, D_FF);
  transpose_convert9<<<dim3(D_MODEL / 32, D_FF / 32, 9), tb, 0, stream>>>(
      sw2, ew2, w2t, D_FF, D_MODEL);

  router_kernel<<<T_TOK / 4, 256, 0, stream>>>(x, rw, rb, sel_idx, sel_w, counts);
  scan_kernel<<<1, 64, 0, stream>>>(counts, offsets, cursor);
  assign_kernel<<<T_TOK / 256, 256, 0, stream>>>(sel_idx, cursor, rows, inv);

  gemm_kernel<1><<<dim3(D_FF / 128, T_TOK / 128, 9), 256, 0, stream>>>(
      xb, w1t, sb1, eb1, H, nullptr, nullptr, rows, counts, offsets);
  gemm_kernel<2><<<dim3(D_MODEL / 128, T_TOK / 128, 9), 256, 0, stream>>>(
      H, w2t, sb2, eb2, nullptr, out, Yexp, rows, counts, offsets);

  combine_kernel<<<T_TOK, 256, 0, stream>>>(out, Yexp, inv, sel_w);
}

// Round 4
// 1060.893 us; speedup vs baseline: 1.2678x; 1.0441x over previous
//
#include <hip/hip_runtime.h>
#include <hip/hip_bf16.h>

// ---------------------------------------------------------------------------
// SharedSpecialistMoEFFN on MI355X (gfx950) — round 7
//
// R6 post-mortem: 32x32 MFMA frags broke the (row&7)-keyed XOR swizzle
// (rows=lane&31 -> 4 same-residue lanes/half-wave -> 4-way LDS conflict,
// 2.57e7 counted); XCD swizzle gave no FETCH reduction (W already L2-hit).
// Both reverted -> exact R3 GEMM (354us, 0 conflicts, 2.6 blocks/CU).
// R7 levers (in-structure, low-risk):
//  1. VALUBusy 44% vs MfmaUtil 26% with trivial K-loop VALU => epilogue
//     gelu/erff (64 calls/thread, ~25-30 VALU instrs each) is ~1/3 of VALU.
//     Replace with Abramowitz-Stegun 7.1.26 erf (|err|<=1.5e-7 << fp16
//     rounding of H; ~13 instrs, exp/rcp on trans pipe).
//  2. Transpose kernels: 64x32 tiles, half2 packed writes -> 128B/32-lane
//     stores (was 64B), halving write fragmentation of 144MB of traffic.
// ---------------------------------------------------------------------------

#define D_MODEL 1024
#define D_FF    4096
#define N_EXP   8
#define T_TOK   8192
#define BK      64

typedef _Float16 half8  __attribute__((ext_vector_type(8)));
typedef _Float16 half4v __attribute__((ext_vector_type(4)));
typedef _Float16 half2v __attribute__((ext_vector_type(2)));
typedef float    floatx4 __attribute__((ext_vector_type(4)));

// A&S 7.1.26 erf approx: |err| <= 1.5e-7 (~300x below fp16 rounding of H).
// exp/rcp map to the transcendental pipe and overlap VALU issue.
__device__ __forceinline__ float gelu_fast(float x) {
  float ax = fabsf(x) * 0.70710678118654752f;     // |x|/sqrt(2)
  float t  = __builtin_amdgcn_rcpf(fmaf(0.3275911f, ax, 1.0f));
  float e  = __expf(-ax * ax);
  float p  = t * fmaf(t, fmaf(t, fmaf(t, fmaf(t, 1.061405429f, -1.453152027f),
                                      1.421413741f), -0.284496736f),
                      0.254829592f);
  float erfv = fmaf(-p, e, 1.0f);                 // erf(|x|/sqrt2) for x>=0
  float s = copysignf(erfv, x);
  return 0.5f * x * (1.0f + s);
}

__device__ __forceinline__ void gld_lds16(const _Float16* g, _Float16* l) {
  __builtin_amdgcn_global_load_lds(
      (const __attribute__((address_space(1))) void*)g,
      (__attribute__((address_space(3))) void*)l, 16, 0, 0);
}

// ---------------------------------------------------------------- converts
__global__ void convert_f32_f16(const float* __restrict__ src,
                                _Float16* __restrict__ dst, int n4) {
  int i = blockIdx.x * blockDim.x + threadIdx.x;
  if (i >= n4) return;
  float4 v = ((const float4*)src)[i];
  half4v h;
  h[0] = (_Float16)v.x; h[1] = (_Float16)v.y;
  h[2] = (_Float16)v.z; h[3] = (_Float16)v.w;
  ((half4v*)dst)[i] = h;
}

// z=0: shared weight, z>=1: expert z-1.  src fp32 [R][C] -> dst fp16 [C][R].
// 64-row x 32-col source tile; write side: 32 lanes x half2 = 128B stores.
__global__ void transpose_convert9(const float* __restrict__ srcSh,
                                   const float* __restrict__ srcEx,
                                   _Float16* __restrict__ dst, int R, int C) {
  const size_t msz = (size_t)R * C;
  const float* src = (blockIdx.z == 0) ? srcSh : srcEx + msz * (blockIdx.z - 1);
  _Float16* d = dst + msz * blockIdx.z;
  __shared__ float tile[64][33];
  int c0 = blockIdx.x * 32, r0 = blockIdx.y * 64;
  int tx = threadIdx.x, ty = threadIdx.y;   // block (32, 8)
#pragma unroll
  for (int i = 0; i < 8; ++i)
    tile[ty + i * 8][tx] = src[(size_t)(r0 + ty + i * 8) * C + c0 + tx];
  __syncthreads();
#pragma unroll
  for (int i = 0; i < 4; ++i) {
    const int c = ty + i * 8;               // source col = dst row
    half2v v;
    v[0] = (_Float16)tile[2 * tx][c];       // banks (2tx+c)%32: 2-way, free
    v[1] = (_Float16)tile[2 * tx + 1][c];
    *(half2v*)(d + (size_t)(c0 + c) * R + r0 + 2 * tx) = v;
  }
}

// ---------------------------------------------------------------- router
__global__ void router_kernel(const float* __restrict__ x,
                              const float* __restrict__ rw,
                              const float* __restrict__ rb,
                              int* __restrict__ sel_idx,
                              float* __restrict__ sel_w,
                              int* __restrict__ counts) {
  int lane = threadIdx.x & 63;
  int t = blockIdx.x * 4 + (threadIdx.x >> 6);
  const float* xr = x + (size_t)t * D_MODEL;
  float acc[N_EXP];
#pragma unroll
  for (int e = 0; e < N_EXP; ++e) acc[e] = 0.f;
  for (int k = lane; k < D_MODEL; k += 64) {
    float xv = xr[k];
    const float* w = rw + (size_t)k * N_EXP;
#pragma unroll
    for (int e = 0; e < N_EXP; ++e) acc[e] += xv * w[e];
  }
#pragma unroll
  for (int off = 32; off > 0; off >>= 1) {
#pragma unroll
    for (int e = 0; e < N_EXP; ++e)
      acc[e] += __shfl_down(acc[e], off, 64);
  }
  if (lane == 0) {
    float mx = -1e30f;
#pragma unroll
    for (int e = 0; e < N_EXP; ++e) { acc[e] += rb[e]; mx = fmaxf(mx, acc[e]); }
    float p[N_EXP], s = 0.f;
#pragma unroll
    for (int e = 0; e < N_EXP; ++e) { p[e] = expf(acc[e] - mx); s += p[e]; }
    float inv = 1.f / s;
#pragma unroll
    for (int e = 0; e < N_EXP; ++e) p[e] *= inv;
    int i0 = 0; float p0 = p[0];
#pragma unroll
    for (int e = 1; e < N_EXP; ++e) if (p[e] > p0) { p0 = p[e]; i0 = e; }
    int i1 = -1; float p1 = -1.f;
#pragma unroll
    for (int e = 0; e < N_EXP; ++e)
      if (e != i0 && p[e] > p1) { p1 = p[e]; i1 = e; }
    float s2 = p0 + p1 + 1e-9f;
    sel_idx[2 * t] = i0; sel_idx[2 * t + 1] = i1;
    sel_w[2 * t] = p0 / s2; sel_w[2 * t + 1] = p1 / s2;
    atomicAdd(&counts[i0 * 32], 1);
    atomicAdd(&counts[i1 * 32], 1);
  }
}

__global__ void scan_kernel(const int* __restrict__ counts,
                            int* __restrict__ offsets,
                            int* __restrict__ cursor) {
  if (threadIdx.x == 0) {
    int s = 0;
    for (int e = 0; e < N_EXP; ++e) {
      offsets[e] = s; cursor[e * 32] = s; s += counts[e * 32];
    }
    offsets[N_EXP] = s;
  }
}

__global__ void assign_kernel(const int* __restrict__ sel_idx,
                              int* __restrict__ cursor,
                              int* __restrict__ rows,
                              int* __restrict__ inv) {
  int t = blockIdx.x * blockDim.x + threadIdx.x;
  if (t >= T_TOK) return;
#pragma unroll
  for (int k = 0; k < 2; ++k) {
    int e = sel_idx[2 * t + k];
    int pos = atomicAdd(&cursor[e * 32], 1);
    rows[pos] = t;
    inv[2 * t + k] = pos;
  }
}

// ---------------------------------------------------------------- GEMM
// PHASE 1: FFN1  K=1024, N=4096.  z=0: H[m]=gelu(xb[m]@W1sh+b); z>=1:
//          H[T+offs+m]=gelu(xb[rows[offs+m]]@W1e+b).   fp16 stores.
// PHASE 2: FFN2  K=4096, N=1024.  z=0: out[m]=H[m]@W2sh+b (fp32); z>=1:
//          Yexp[offs+m]=H[T+offs+m]@W2e+b (fp32, gathered order).
// 128x128 tile, BK=64, 256 thr (2x2 waves of 64x64), XOR-swizzled staging.
// bounds(256,3): 170-reg cap — acc(64)+frags(16)+ptrs(~20)+misc fits, NO SPILL.
template <int PHASE>
__global__ __launch_bounds__(256, 3) void gemm_kernel(
    const _Float16* __restrict__ A, const _Float16* __restrict__ Wt,
    const float* __restrict__ biasSh, const float* __restrict__ biasEx,
    _Float16* __restrict__ Hout, float* __restrict__ out,
    float* __restrict__ Yexp, const int* __restrict__ rows,
    const int* __restrict__ counts, const int* __restrict__ offsets) {
  constexpr int K = (PHASE == 1) ? D_MODEL : D_FF;
  constexpr int N = (PHASE == 1) ? D_FF : D_MODEL;
  const int z = blockIdx.z;
  int M = T_TOK, offs = 0;
  if (z > 0) {
    M = counts[(z - 1) * 32];
    offs = offsets[z - 1];
    if ((int)blockIdx.y * 128 >= M) return;   // uniform early-exit
  }
  const int tid = threadIdx.x, lane = tid & 63, wid = tid >> 6;
  const int m0 = blockIdx.y * 128, n0 = blockIdx.x * 128;
  const _Float16* Wz = Wt + (size_t)z * N * K;

  __shared__ __align__(16) _Float16 As[128 * BK];  // [m][k], k-chunks swizzled
  __shared__ __align__(16) _Float16 Bs[128 * BK];  // [n][k]

  // staging: 16 chunk-groups of 8 rows x 128 B; wave w fills groups 4w..4w+3.
  // lane i -> row sub=i>>3 of the group, physical 16B slot p=i&7 holding
  // GLOBAL k-chunk g = p ^ sub  (XOR swizzle).
  const int sub = lane >> 3, pp = lane & 7, g = pp ^ sub;

  int r0i = m0 + (wid * 4 + 0) * 8 + sub;
  int r1i = m0 + (wid * 4 + 1) * 8 + sub;
  int r2i = m0 + (wid * 4 + 2) * 8 + sub;
  int r3i = m0 + (wid * 4 + 3) * 8 + sub;
  size_t gr0, gr1, gr2, gr3;
  if (z == 0) {
    gr0 = (size_t)r0i; gr1 = (size_t)r1i; gr2 = (size_t)r2i; gr3 = (size_t)r3i;
  } else if constexpr (PHASE == 1) {
    gr0 = (size_t)rows[offs + (r0i < M ? r0i : M - 1)];
    gr1 = (size_t)rows[offs + (r1i < M ? r1i : M - 1)];
    gr2 = (size_t)rows[offs + (r2i < M ? r2i : M - 1)];
    gr3 = (size_t)rows[offs + (r3i < M ? r3i : M - 1)];
  } else {
    gr0 = (size_t)(T_TOK + offs + (r0i < M ? r0i : M - 1));
    gr1 = (size_t)(T_TOK + offs + (r1i < M ? r1i : M - 1));
    gr2 = (size_t)(T_TOK + offs + (r2i < M ? r2i : M - 1));
    gr3 = (size_t)(T_TOK + offs + (r3i < M ? r3i : M - 1));
  }
  const _Float16* aS0 = A + gr0 * K + g * 8;
  const _Float16* aS1 = A + gr1 * K + g * 8;
  const _Float16* aS2 = A + gr2 * K + g * 8;
  const _Float16* aS3 = A + gr3 * K + g * 8;
  const _Float16* bS0 = Wz + (size_t)(n0 + (wid * 4 + 0) * 8 + sub) * K + g * 8;
  const _Float16* bS1 = Wz + (size_t)(n0 + (wid * 4 + 1) * 8 + sub) * K + g * 8;
  const _Float16* bS2 = Wz + (size_t)(n0 + (wid * 4 + 2) * 8 + sub) * K + g * 8;
  const _Float16* bS3 = Wz + (size_t)(n0 + (wid * 4 + 3) * 8 + sub) * K + g * 8;

  floatx4 acc[4][4] = {};
  const int wm = wid >> 1, wn = wid & 1;
  const int lr = lane & 15, qd = lane >> 4;

  for (int kt = 0; kt < K; kt += BK) {
    __syncthreads();
    gld_lds16(aS0, As + (wid * 4 + 0) * 512);
    gld_lds16(aS1, As + (wid * 4 + 1) * 512);
    gld_lds16(aS2, As + (wid * 4 + 2) * 512);
    gld_lds16(aS3, As + (wid * 4 + 3) * 512);
    gld_lds16(bS0, Bs + (wid * 4 + 0) * 512);
    gld_lds16(bS1, Bs + (wid * 4 + 1) * 512);
    gld_lds16(bS2, Bs + (wid * 4 + 2) * 512);
    gld_lds16(bS3, Bs + (wid * 4 + 3) * 512);
    aS0 += BK; aS1 += BK; aS2 += BK; aS3 += BK;
    bS0 += BK; bS1 += BK; bS2 += BK; bS3 += BK;
    asm volatile("s_waitcnt vmcnt(0)" ::: "memory");
    __syncthreads();
#pragma unroll
    for (int h = 0; h < 2; ++h) {
      half8 af[4], bf[4];
#pragma unroll
      for (int mi = 0; mi < 4; ++mi) {
        const int r = wm * 64 + mi * 16 + lr;
        const int slot = (h * 4 + qd) ^ (r & 7);
        af[mi] = *(const half8*)(As + r * BK + slot * 8);
      }
#pragma unroll
      for (int ni = 0; ni < 4; ++ni) {
        const int r = wn * 64 + ni * 16 + lr;
        const int slot = (h * 4 + qd) ^ (r & 7);
        bf[ni] = *(const half8*)(Bs + r * BK + slot * 8);
      }
#pragma unroll
      for (int mi = 0; mi < 4; ++mi)
#pragma unroll
        for (int ni = 0; ni < 4; ++ni)
          acc[mi][ni] = __builtin_amdgcn_mfma_f32_16x16x32_f16(
              af[mi], bf[ni], acc[mi][ni], 0, 0, 0);
    }
  }

  // epilogue: C/D layout col=lane&15, row=quad*4+reg (R1-verified)
  const float* be = (z == 0) ? biasSh : biasEx + (size_t)(z - 1) * N;
#pragma unroll
  for (int mi = 0; mi < 4; ++mi) {
#pragma unroll
    for (int ni = 0; ni < 4; ++ni) {
      floatx4 v = acc[mi][ni];
#pragma unroll
      for (int r4 = 0; r4 < 4; ++r4) {
        const int lrow = m0 + wm * 64 + mi * 16 + qd * 4 + r4;  // row in segment
        const int col = n0 + wn * 64 + ni * 16 + lr;
        const float val = v[r4] + be[col];
        if constexpr (PHASE == 1) {
          if (z == 0) {
            Hout[(size_t)lrow * N + col] = (_Float16)gelu_fast(val);
          } else if (lrow < M) {
            Hout[(size_t)(T_TOK + offs + lrow) * N + col] =
                (_Float16)gelu_fast(val);
          }
        } else {
          if (z == 0) {
            out[(size_t)lrow * N + col] = val;
          } else if (lrow < M) {
            Yexp[(size_t)(offs + lrow) * N + col] = val;
          }
        }
      }
    }
  }
}

// ---------------------------------------------------------------- combine
// out[t] = out[t] (shared FFN2) + w0*Yexp[p0] + w1*Yexp[p1]
__global__ void combine_kernel(float* __restrict__ out,
                               const float* __restrict__ Yexp,
                               const int* __restrict__ inv,
                               const float* __restrict__ selw) {
  const int t = blockIdx.x;
  const int c = threadIdx.x * 4;
  const int p0 = inv[2 * t], p1 = inv[2 * t + 1];
  const float w0 = selw[2 * t], w1 = selw[2 * t + 1];
  float4 o = *(float4*)(out + (size_t)t * D_MODEL + c);
  const float4 a = *(const float4*)(Yexp + (size_t)p0 * D_MODEL + c);
  const float4 b = *(const float4*)(Yexp + (size_t)p1 * D_MODEL + c);
  o.x += w0 * a.x + w1 * b.x;
  o.y += w0 * a.y + w1 * b.y;
  o.z += w0 * a.z + w1 * b.z;
  o.w += w0 * a.w + w1 * b.w;
  *(float4*)(out + (size_t)t * D_MODEL + c) = o;
}

// ---------------------------------------------------------------- launch
extern "C" void kernel_launch(void* const* d_in, const int* in_sizes, int n_in,
                              void* d_out, int out_size, void* d_ws,
                              size_t ws_size, hipStream_t stream) {
  const float* x   = (const float*)d_in[0];
  const float* sw1 = (const float*)d_in[1];
  const float* sb1 = (const float*)d_in[2];
  const float* sw2 = (const float*)d_in[3];
  const float* sb2 = (const float*)d_in[4];
  const float* rw  = (const float*)d_in[5];
  const float* rb  = (const float*)d_in[6];
  const float* ew1 = (const float*)d_in[7];
  const float* eb1 = (const float*)d_in[8];
  const float* ew2 = (const float*)d_in[9];
  const float* eb2 = (const float*)d_in[10];
  float* out = (float*)d_out;

  char* ws = (char*)d_ws;
  size_t off = 0;
  auto alloc = [&](size_t bytes) {
    void* p = ws + off;
    off += (bytes + 255) & ~(size_t)255;
    return p;
  };
  _Float16* xb  = (_Float16*)alloc((size_t)T_TOK * D_MODEL * 2);        // 16 MB
  _Float16* w2t = (_Float16*)alloc((size_t)9 * D_MODEL * D_FF * 2);     // 72 MB
  _Float16* H   = (_Float16*)alloc((size_t)3 * T_TOK * D_FF * 2);       // 201 MB
  _Float16* w1t = (_Float16*)alloc((size_t)9 * D_FF * D_MODEL * 2);     // 72 MB
  float* Yexp   = (float*)w1t;  // alias: w1t dead after FFN1, Yexp 67 MB
  int*   sel_idx = (int*)alloc((size_t)T_TOK * 2 * 4);
  float* sel_w   = (float*)alloc((size_t)T_TOK * 2 * 4);
  int*   rows    = (int*)alloc((size_t)2 * T_TOK * 4);
  int*   inv     = (int*)alloc((size_t)2 * T_TOK * 4);
  int*   counts  = (int*)alloc(N_EXP * 32 * 4);
  int*   offsets = (int*)alloc(16 * 4);
  int*   cursor  = (int*)alloc(N_EXP * 32 * 4);
  (void)ws_size; (void)in_sizes; (void)n_in; (void)out_size;

  hipMemsetAsync(counts, 0, N_EXP * 32 * 4, stream);

  convert_f32_f16<<<(T_TOK * D_MODEL / 4 + 255) / 256, 256, 0, stream>>>(
      x, xb, T_TOK * D_MODEL / 4);
  dim3 tb(32, 8);
  // W1: [1024][4096] -> [4096][1024];  W2: [4096][1024] -> [1024][4096]
  transpose_convert9<<<dim3(D_FF / 32, D_MODEL / 64, 9), tb, 0, stream>>>(
      sw1, ew1, w1t, D_MODEL, D_FF);
  transpose_convert9<<<dim3(D_MODEL / 32, D_FF / 64, 9), tb, 0, stream>>>(
      sw2, ew2, w2t, D_FF, D_MODEL);

  router_kernel<<<T_TOK / 4, 256, 0, stream>>>(x, rw, rb, sel_idx, sel_w, counts);
  scan_kernel<<<1, 64, 0, stream>>>(counts, offsets, cursor);
  assign_kernel<<<T_TOK / 256, 256, 0, stream>>>(sel_idx, cursor, rows, inv);

  gemm_kernel<1><<<dim3(D_FF / 128, T_TOK / 128, 9), 256, 0, stream>>>(
      xb, w1t, sb1, eb1, H, nullptr, nullptr, rows, counts, offsets);
  gemm_kernel<2><<<dim3(D_MODEL / 128, T_TOK / 128, 9), 256, 0, stream>>>(
      H, w2t, sb2, eb2, nullptr, out, Yexp, rows, counts, offsets);

  combine_kernel<<<T_TOK, 256, 0, stream>>>(out, Yexp, inv, sel_w);
}

// Round 5
// 1036.866 us; speedup vs baseline: 1.2972x; 1.0232x over previous
//
#include <hip/hip_runtime.h>
#include <hip/hip_bf16.h>

// ---------------------------------------------------------------------------
// SharedSpecialistMoEFFN on MI355X (gfx950) — round 8
//
// R7 post-mortem: fast-gelu worked (gemm1 354->312, VALUBusy 44->39.5).
// gemm2 now dominant: FETCH 850MB (H=201MB re-read by 8 N-panels, thrashes
// the 256MB L3), MfmaUtil 28%, VALU 13% -> fetch/latency-coupled; the
// per-K-tile vmcnt(0) drain waits on HBM (~900cy) instead of L2 (~200cy).
// R8: XCD-affinity Y-GROUPING (bijective remap, speed-only): y-panel by ->
// XCD by%8 (assumes linearID%8 round-robin), with all 8 x-blocks of that
// panel co-resident+adjacent on the same XCD -> H-panel (1MB) fetched once
// into that XCD's 4MB L2; W2 streams from L3 (72MB, L3-resident). R6's
// failed swizzle grouped same-bx (shared W) - wrong axis; the re-read
// stream is A (same-by). Applied to both phases (gemm1: xb panels pinned).
// ---------------------------------------------------------------------------

#define D_MODEL 1024
#define D_FF    4096
#define N_EXP   8
#define T_TOK   8192
#define BK      64

typedef _Float16 half8  __attribute__((ext_vector_type(8)));
typedef _Float16 half4v __attribute__((ext_vector_type(4)));
typedef _Float16 half2v __attribute__((ext_vector_type(2)));
typedef float    floatx4 __attribute__((ext_vector_type(4)));

// A&S 7.1.26 erf approx: |err| <= 1.5e-7 (~300x below fp16 rounding of H).
__device__ __forceinline__ float gelu_fast(float x) {
  float ax = fabsf(x) * 0.70710678118654752f;     // |x|/sqrt(2)
  float t  = __builtin_amdgcn_rcpf(fmaf(0.3275911f, ax, 1.0f));
  float e  = __expf(-ax * ax);
  float p  = t * fmaf(t, fmaf(t, fmaf(t, fmaf(t, 1.061405429f, -1.453152027f),
                                      1.421413741f), -0.284496736f),
                      0.254829592f);
  float erfv = fmaf(-p, e, 1.0f);                 // erf(|x|/sqrt2) for x>=0
  float s = copysignf(erfv, x);
  return 0.5f * x * (1.0f + s);
}

__device__ __forceinline__ void gld_lds16(const _Float16* g, _Float16* l) {
  __builtin_amdgcn_global_load_lds(
      (const __attribute__((address_space(1))) void*)g,
      (__attribute__((address_space(3))) void*)l, 16, 0, 0);
}

// ---------------------------------------------------------------- converts
__global__ void convert_f32_f16(const float* __restrict__ src,
                                _Float16* __restrict__ dst, int n4) {
  int i = blockIdx.x * blockDim.x + threadIdx.x;
  if (i >= n4) return;
  float4 v = ((const float4*)src)[i];
  half4v h;
  h[0] = (_Float16)v.x; h[1] = (_Float16)v.y;
  h[2] = (_Float16)v.z; h[3] = (_Float16)v.w;
  ((half4v*)dst)[i] = h;
}

// z=0: shared weight, z>=1: expert z-1.  src fp32 [R][C] -> dst fp16 [C][R].
// 64-row x 32-col source tile; write side: 32 lanes x half2 = 128B stores.
__global__ void transpose_convert9(const float* __restrict__ srcSh,
                                   const float* __restrict__ srcEx,
                                   _Float16* __restrict__ dst, int R, int C) {
  const size_t msz = (size_t)R * C;
  const float* src = (blockIdx.z == 0) ? srcSh : srcEx + msz * (blockIdx.z - 1);
  _Float16* d = dst + msz * blockIdx.z;
  __shared__ float tile[64][33];
  int c0 = blockIdx.x * 32, r0 = blockIdx.y * 64;
  int tx = threadIdx.x, ty = threadIdx.y;   // block (32, 8)
#pragma unroll
  for (int i = 0; i < 8; ++i)
    tile[ty + i * 8][tx] = src[(size_t)(r0 + ty + i * 8) * C + c0 + tx];
  __syncthreads();
#pragma unroll
  for (int i = 0; i < 4; ++i) {
    const int c = ty + i * 8;               // source col = dst row
    half2v v;
    v[0] = (_Float16)tile[2 * tx][c];       // banks (2tx+c)%32: 2-way, free
    v[1] = (_Float16)tile[2 * tx + 1][c];
    *(half2v*)(d + (size_t)(c0 + c) * R + r0 + 2 * tx) = v;
  }
}

// ---------------------------------------------------------------- router
__global__ void router_kernel(const float* __restrict__ x,
                              const float* __restrict__ rw,
                              const float* __restrict__ rb,
                              int* __restrict__ sel_idx,
                              float* __restrict__ sel_w,
                              int* __restrict__ counts) {
  int lane = threadIdx.x & 63;
  int t = blockIdx.x * 4 + (threadIdx.x >> 6);
  const float* xr = x + (size_t)t * D_MODEL;
  float acc[N_EXP];
#pragma unroll
  for (int e = 0; e < N_EXP; ++e) acc[e] = 0.f;
  for (int k = lane; k < D_MODEL; k += 64) {
    float xv = xr[k];
    const float* w = rw + (size_t)k * N_EXP;
#pragma unroll
    for (int e = 0; e < N_EXP; ++e) acc[e] += xv * w[e];
  }
#pragma unroll
  for (int off = 32; off > 0; off >>= 1) {
#pragma unroll
    for (int e = 0; e < N_EXP; ++e)
      acc[e] += __shfl_down(acc[e], off, 64);
  }
  if (lane == 0) {
    float mx = -1e30f;
#pragma unroll
    for (int e = 0; e < N_EXP; ++e) { acc[e] += rb[e]; mx = fmaxf(mx, acc[e]); }
    float p[N_EXP], s = 0.f;
#pragma unroll
    for (int e = 0; e < N_EXP; ++e) { p[e] = expf(acc[e] - mx); s += p[e]; }
    float inv = 1.f / s;
#pragma unroll
    for (int e = 0; e < N_EXP; ++e) p[e] *= inv;
    int i0 = 0; float p0 = p[0];
#pragma unroll
    for (int e = 1; e < N_EXP; ++e) if (p[e] > p0) { p0 = p[e]; i0 = e; }
    int i1 = -1; float p1 = -1.f;
#pragma unroll
    for (int e = 0; e < N_EXP; ++e)
      if (e != i0 && p[e] > p1) { p1 = p[e]; i1 = e; }
    float s2 = p0 + p1 + 1e-9f;
    sel_idx[2 * t] = i0; sel_idx[2 * t + 1] = i1;
    sel_w[2 * t] = p0 / s2; sel_w[2 * t + 1] = p1 / s2;
    atomicAdd(&counts[i0 * 32], 1);
    atomicAdd(&counts[i1 * 32], 1);
  }
}

__global__ void scan_kernel(const int* __restrict__ counts,
                            int* __restrict__ offsets,
                            int* __restrict__ cursor) {
  if (threadIdx.x == 0) {
    int s = 0;
    for (int e = 0; e < N_EXP; ++e) {
      offsets[e] = s; cursor[e * 32] = s; s += counts[e * 32];
    }
    offsets[N_EXP] = s;
  }
}

__global__ void assign_kernel(const int* __restrict__ sel_idx,
                              int* __restrict__ cursor,
                              int* __restrict__ rows,
                              int* __restrict__ inv) {
  int t = blockIdx.x * blockDim.x + threadIdx.x;
  if (t >= T_TOK) return;
#pragma unroll
  for (int k = 0; k < 2; ++k) {
    int e = sel_idx[2 * t + k];
    int pos = atomicAdd(&cursor[e * 32], 1);
    rows[pos] = t;
    inv[2 * t + k] = pos;
  }
}

// ---------------------------------------------------------------- GEMM
// PHASE 1: FFN1  K=1024, N=4096.  PHASE 2: FFN2  K=4096, N=1024.
// 128x128 tile, BK=64, 256 thr (2x2 waves of 64x64), XOR-swizzled staging.
// XCD y-grouping: y-panel by -> XCD by%8; its x-blocks adjacent on that XCD
// so the A(H/xb)-panel is fetched once into the XCD's L2 (speed-only remap).
template <int PHASE>
__global__ __launch_bounds__(256, 3) void gemm_kernel(
    const _Float16* __restrict__ A, const _Float16* __restrict__ Wt,
    const float* __restrict__ biasSh, const float* __restrict__ biasEx,
    _Float16* __restrict__ Hout, float* __restrict__ out,
    float* __restrict__ Yexp, const int* __restrict__ rows,
    const int* __restrict__ counts, const int* __restrict__ offsets) {
  constexpr int K = (PHASE == 1) ? D_MODEL : D_FF;
  constexpr int N = (PHASE == 1) ? D_FF : D_MODEL;
  constexpr int GX = N / 128;               // 32 (phase1) / 8 (phase2)
  // ---- bijective XCD y-grouping remap (assumes XCD = linearID % 8)
  // L = c*(8*GX) + p*8 + k  ->  by = c*8 + k (XCD k), bx = p
  const int L = (int)blockIdx.y * GX + (int)blockIdx.x;
  const int kx = L & 7;
  const int cc = L / (8 * GX);
  const int pp2 = (L % (8 * GX)) >> 3;
  const int by = cc * 8 + kx, bx = pp2;

  const int z = blockIdx.z;
  int M = T_TOK, offs = 0;
  if (z > 0) {
    M = counts[(z - 1) * 32];
    offs = offsets[z - 1];
    if (by * 128 >= M) return;              // uniform early-exit
  }
  const int tid = threadIdx.x, lane = tid & 63, wid = tid >> 6;
  const int m0 = by * 128, n0 = bx * 128;
  const _Float16* Wz = Wt + (size_t)z * N * K;

  __shared__ __align__(16) _Float16 As[128 * BK];  // [m][k], k-chunks swizzled
  __shared__ __align__(16) _Float16 Bs[128 * BK];  // [n][k]

  // staging: 16 chunk-groups of 8 rows x 128 B; wave w fills groups 4w..4w+3.
  // lane i -> row sub=i>>3 of the group, physical 16B slot p=i&7 holding
  // GLOBAL k-chunk g = p ^ sub  (XOR swizzle).
  const int sub = lane >> 3, pl = lane & 7, g = pl ^ sub;

  int r0i = m0 + (wid * 4 + 0) * 8 + sub;
  int r1i = m0 + (wid * 4 + 1) * 8 + sub;
  int r2i = m0 + (wid * 4 + 2) * 8 + sub;
  int r3i = m0 + (wid * 4 + 3) * 8 + sub;
  size_t gr0, gr1, gr2, gr3;
  if (z == 0) {
    gr0 = (size_t)r0i; gr1 = (size_t)r1i; gr2 = (size_t)r2i; gr3 = (size_t)r3i;
  } else if constexpr (PHASE == 1) {
    gr0 = (size_t)rows[offs + (r0i < M ? r0i : M - 1)];
    gr1 = (size_t)rows[offs + (r1i < M ? r1i : M - 1)];
    gr2 = (size_t)rows[offs + (r2i < M ? r2i : M - 1)];
    gr3 = (size_t)rows[offs + (r3i < M ? r3i : M - 1)];
  } else {
    gr0 = (size_t)(T_TOK + offs + (r0i < M ? r0i : M - 1));
    gr1 = (size_t)(T_TOK + offs + (r1i < M ? r1i : M - 1));
    gr2 = (size_t)(T_TOK + offs + (r2i < M ? r2i : M - 1));
    gr3 = (size_t)(T_TOK + offs + (r3i < M ? r3i : M - 1));
  }
  const _Float16* aS0 = A + gr0 * K + g * 8;
  const _Float16* aS1 = A + gr1 * K + g * 8;
  const _Float16* aS2 = A + gr2 * K + g * 8;
  const _Float16* aS3 = A + gr3 * K + g * 8;
  const _Float16* bS0 = Wz + (size_t)(n0 + (wid * 4 + 0) * 8 + sub) * K + g * 8;
  const _Float16* bS1 = Wz + (size_t)(n0 + (wid * 4 + 1) * 8 + sub) * K + g * 8;
  const _Float16* bS2 = Wz + (size_t)(n0 + (wid * 4 + 2) * 8 + sub) * K + g * 8;
  const _Float16* bS3 = Wz + (size_t)(n0 + (wid * 4 + 3) * 8 + sub) * K + g * 8;

  floatx4 acc[4][4] = {};
  const int wm = wid >> 1, wn = wid & 1;
  const int lr = lane & 15, qd = lane >> 4;

  for (int kt = 0; kt < K; kt += BK) {
    __syncthreads();
    gld_lds16(aS0, As + (wid * 4 + 0) * 512);
    gld_lds16(aS1, As + (wid * 4 + 1) * 512);
    gld_lds16(aS2, As + (wid * 4 + 2) * 512);
    gld_lds16(aS3, As + (wid * 4 + 3) * 512);
    gld_lds16(bS0, Bs + (wid * 4 + 0) * 512);
    gld_lds16(bS1, Bs + (wid * 4 + 1) * 512);
    gld_lds16(bS2, Bs + (wid * 4 + 2) * 512);
    gld_lds16(bS3, Bs + (wid * 4 + 3) * 512);
    aS0 += BK; aS1 += BK; aS2 += BK; aS3 += BK;
    bS0 += BK; bS1 += BK; bS2 += BK; bS3 += BK;
    asm volatile("s_waitcnt vmcnt(0)" ::: "memory");
    __syncthreads();
#pragma unroll
    for (int h = 0; h < 2; ++h) {
      half8 af[4], bf[4];
#pragma unroll
      for (int mi = 0; mi < 4; ++mi) {
        const int r = wm * 64 + mi * 16 + lr;
        const int slot = (h * 4 + qd) ^ (r & 7);
        af[mi] = *(const half8*)(As + r * BK + slot * 8);
      }
#pragma unroll
      for (int ni = 0; ni < 4; ++ni) {
        const int r = wn * 64 + ni * 16 + lr;
        const int slot = (h * 4 + qd) ^ (r & 7);
        bf[ni] = *(const half8*)(Bs + r * BK + slot * 8);
      }
#pragma unroll
      for (int mi = 0; mi < 4; ++mi)
#pragma unroll
        for (int ni = 0; ni < 4; ++ni)
          acc[mi][ni] = __builtin_amdgcn_mfma_f32_16x16x32_f16(
              af[mi], bf[ni], acc[mi][ni], 0, 0, 0);
    }
  }

  // epilogue: C/D layout col=lane&15, row=quad*4+reg (R1-verified)
  const float* be = (z == 0) ? biasSh : biasEx + (size_t)(z - 1) * N;
#pragma unroll
  for (int mi = 0; mi < 4; ++mi) {
#pragma unroll
    for (int ni = 0; ni < 4; ++ni) {
      floatx4 v = acc[mi][ni];
#pragma unroll
      for (int r4 = 0; r4 < 4; ++r4) {
        const int lrow = m0 + wm * 64 + mi * 16 + qd * 4 + r4;  // row in segment
        const int col = n0 + wn * 64 + ni * 16 + lr;
        const float val = v[r4] + be[col];
        if constexpr (PHASE == 1) {
          if (z == 0) {
            Hout[(size_t)lrow * N + col] = (_Float16)gelu_fast(val);
          } else if (lrow < M) {
            Hout[(size_t)(T_TOK + offs + lrow) * N + col] =
                (_Float16)gelu_fast(val);
          }
        } else {
          if (z == 0) {
            out[(size_t)lrow * N + col] = val;
          } else if (lrow < M) {
            Yexp[(size_t)(offs + lrow) * N + col] = val;
          }
        }
      }
    }
  }
}

// ---------------------------------------------------------------- combine
// out[t] = out[t] (shared FFN2) + w0*Yexp[p0] + w1*Yexp[p1]
__global__ void combine_kernel(float* __restrict__ out,
                               const float* __restrict__ Yexp,
                               const int* __restrict__ inv,
                               const float* __restrict__ selw) {
  const int t = blockIdx.x;
  const int c = threadIdx.x * 4;
  const int p0 = inv[2 * t], p1 = inv[2 * t + 1];
  const float w0 = selw[2 * t], w1 = selw[2 * t + 1];
  float4 o = *(float4*)(out + (size_t)t * D_MODEL + c);
  const float4 a = *(const float4*)(Yexp + (size_t)p0 * D_MODEL + c);
  const float4 b = *(const float4*)(Yexp + (size_t)p1 * D_MODEL + c);
  o.x += w0 * a.x + w1 * b.x;
  o.y += w0 * a.y + w1 * b.y;
  o.z += w0 * a.z + w1 * b.z;
  o.w += w0 * a.w + w1 * b.w;
  *(float4*)(out + (size_t)t * D_MODEL + c) = o;
}

// ---------------------------------------------------------------- launch
extern "C" void kernel_launch(void* const* d_in, const int* in_sizes, int n_in,
                              void* d_out, int out_size, void* d_ws,
                              size_t ws_size, hipStream_t stream) {
  const float* x   = (const float*)d_in[0];
  const float* sw1 = (const float*)d_in[1];
  const float* sb1 = (const float*)d_in[2];
  const float* sw2 = (const float*)d_in[3];
  const float* sb2 = (const float*)d_in[4];
  const float* rw  = (const float*)d_in[5];
  const float* rb  = (const float*)d_in[6];
  const float* ew1 = (const float*)d_in[7];
  const float* eb1 = (const float*)d_in[8];
  const float* ew2 = (const float*)d_in[9];
  const float* eb2 = (const float*)d_in[10];
  float* out = (float*)d_out;

  char* ws = (char*)d_ws;
  size_t off = 0;
  auto alloc = [&](size_t bytes) {
    void* p = ws + off;
    off += (bytes + 255) & ~(size_t)255;
    return p;
  };
  _Float16* xb  = (_Float16*)alloc((size_t)T_TOK * D_MODEL * 2);        // 16 MB
  _Float16* w2t = (_Float16*)alloc((size_t)9 * D_MODEL * D_FF * 2);     // 72 MB
  _Float16* H   = (_Float16*)alloc((size_t)3 * T_TOK * D_FF * 2);       // 201 MB
  _Float16* w1t = (_Float16*)alloc((size_t)9 * D_FF * D_MODEL * 2);     // 72 MB
  float* Yexp   = (float*)w1t;  // alias: w1t dead after FFN1, Yexp 67 MB
  int*   sel_idx = (int*)alloc((size_t)T_TOK * 2 * 4);
  float* sel_w   = (float*)alloc((size_t)T_TOK * 2 * 4);
  int*   rows    = (int*)alloc((size_t)2 * T_TOK * 4);
  int*   inv     = (int*)alloc((size_t)2 * T_TOK * 4);
  int*   counts  = (int*)alloc(N_EXP * 32 * 4);
  int*   offsets = (int*)alloc(16 * 4);
  int*   cursor  = (int*)alloc(N_EXP * 32 * 4);
  (void)ws_size; (void)in_sizes; (void)n_in; (void)out_size;

  hipMemsetAsync(counts, 0, N_EXP * 32 * 4, stream);

  convert_f32_f16<<<(T_TOK * D_MODEL / 4 + 255) / 256, 256, 0, stream>>>(
      x, xb, T_TOK * D_MODEL / 4);
  dim3 tb(32, 8);
  // W1: [1024][4096] -> [4096][1024];  W2: [4096][1024] -> [1024][4096]
  transpose_convert9<<<dim3(D_FF / 32, D_MODEL / 64, 9), tb, 0, stream>>>(
      sw1, ew1, w1t, D_MODEL, D_FF);
  transpose_convert9<<<dim3(D_MODEL / 32, D_FF / 64, 9), tb, 0, stream>>>(
      sw2, ew2, w2t, D_FF, D_MODEL);

  router_kernel<<<T_TOK / 4, 256, 0, stream>>>(x, rw, rb, sel_idx, sel_w, counts);
  scan_kernel<<<1, 64, 0, stream>>>(counts, offsets, cursor);
  assign_kernel<<<T_TOK / 256, 256, 0, stream>>>(sel_idx, cursor, rows, inv);

  gemm_kernel<1><<<dim3(D_FF / 128, T_TOK / 128, 9), 256, 0, stream>>>(
      xb, w1t, sb1, eb1, H, nullptr, nullptr, rows, counts, offsets);
  gemm_kernel<2><<<dim3(D_MODEL / 128, T_TOK / 128, 9), 256, 0, stream>>>(
      H, w2t, sb2, eb2, nullptr, out, Yexp, rows, counts, offsets);

  combine_kernel<<<T_TOK, 256, 0, stream>>>(out, Yexp, inv, sel_w);
}